// Round 6
// baseline (2606.314 us; speedup 1.0000x reference)
//
#include <hip/hip_runtime.h>

typedef unsigned short u16;
typedef __attribute__((ext_vector_type(8))) short s8;
typedef __attribute__((ext_vector_type(4))) short s4;
typedef __attribute__((ext_vector_type(4))) float f4;

#define N_TRAJ 4096
#define TSTEPS 128
#define LATD   64
#define INPD   128
#define MROWS  8      // trajectories per block (rows 8-15 of tiles are clones)

// bias offsets (floats)
#define OB1 0
#define OB2 128
#define UB1 192
#define UB2 320
#define RB1 384
#define RB2 512
#define NB1 576
#define NB2 704
#define TB1 832
#define TB2 960
#define DTS 1088
#define NBIAS 1216

// packed weight offsets (elements)
#define OFF_UG1 0
#define OFF_RG1 32768
#define OFF_NS1 65536
#define OFF_OD1 98304
#define OFF_UG2 106496
#define OFF_RG2 114688
#define OFF_NS2 122880
#define OFF_OD2 139264
#define OFF_TZ1 147456
#define OFF_TZ2 163840
#define PACK_ELEMS 180224

__device__ u16 g_pack[PACK_ELEMS];
__device__ float g_bias[NBIAS];

__device__ __forceinline__ float b2f(u16 u) {
    union { unsigned int i; float f; } v; v.i = ((unsigned int)u) << 16; return v.f;
}
__device__ __forceinline__ u16 f2b(float f) {
    unsigned int x = __float_as_uint(f);
    unsigned int r = (x + 0x7FFFu + ((x >> 16) & 1u)) >> 16;
    return (u16)r;
}
__device__ __forceinline__ int is_f32(const void* tps) {
    return (*(const unsigned int*)tps) == 0u;  // f32: bits(0.0f)==0; bf16: u16 pair (0, 0x3C81) != 0
}
__device__ __forceinline__ float rdany(const void* a, int i, int isf32) {
    return isf32 ? ((const float*)a)[i] : b2f(((const u16*)a)[i]);
}
__device__ __forceinline__ float sigm(float x) {
    x = fminf(fmaxf(x, -30.f), 30.f);
    float e = __expf(-x);
    return __builtin_amdgcn_rcpf(1.f + e);
}
__device__ __forceinline__ float tanh_(float x) {
    x = fminf(fmaxf(x, -15.f), 15.f);
    float e = __expf(-2.f * x);
    return (1.f - e) * __builtin_amdgcn_rcpf(1.f + e);
}

// A-fragment read from a [16][128] bf16 LDS tile (row stride 256B, XOR swizzled)
__device__ __forceinline__ s8 aread(const u16* buf, int lane, int ks) {
    int row = lane & 15;
    int b = (ks << 6) + ((lane >> 4) << 4);
    int off = (row << 8) + (b ^ ((row & 7) << 4));
    return *(const s8*)((const char*)buf + off);
}
__device__ __forceinline__ void hwrite(u16* buf, int rowt, int col, float v) {
    int off = (rowt << 8) + (((col << 1)) ^ ((rowt & 7) << 4));
    *(u16*)((char*)buf + off) = f2b(v);
}
__device__ __forceinline__ u16 sread(const u16* buf, int rowt, int col) {
    int off = (rowt << 8) + (((col << 1)) ^ ((rowt & 7) << 4));
    return *(const u16*)((const char*)buf + off);
}
// load 4 consecutive x elements as bf16, from either dtype
__device__ __forceinline__ s4 load_x4(const void* data, size_t elemIdx, int isf32) {
    s4 r;
    if (isf32) {
        f4 v = *(const f4*)((const float*)data + elemIdx);
#pragma unroll
        for (int j = 0; j < 4; ++j) r[j] = (short)f2b(v[j]);
    } else {
        r = *(const s4*)((const u16*)data + elemIdx);
    }
    return r;
}

struct PackP {
    const void* src[10];
    const void* tps;
    int Kr[10], Nr[10], KS[10], sz[10];
};

__global__ __launch_bounds__(256) void repack_kernel(PackP p) {
    int gid = blockIdx.x * 256 + threadIdx.x;
    if (gid >= PACK_ELEMS) return;
    int isf32 = is_f32(p.tps);
    int idx = gid, m = 0, base = 0;
    while (m < 10 && idx >= p.sz[m]) { idx -= p.sz[m]; base += p.sz[m]; ++m; }
    if (m >= 10) return;
    int i = idx & 7;
    int l = (idx >> 3) & 63;
    int rest = idx >> 9;
    int ks = rest % p.KS[m];
    int nt = rest / p.KS[m];
    int k = ks * 32 + ((l >> 4) << 3) + i;
    int n = nt * 16 + (l & 15);
    u16 v = 0;
    if (k < p.Kr[m] && n < p.Nr[m]) v = f2b(rdany(p.src[m], k * p.Nr[m] + n, isf32));
    g_pack[base + idx] = v;
}

struct PrepP {
    const void *tps, *ob1, *ob2, *ub1, *ub2, *rb1, *rb2, *nb1, *nb2, *tb1, *tb2;
};

__global__ __launch_bounds__(256) void prep_bias(PrepP p) {
    int isf32 = is_f32(p.tps);
    int tid = threadIdx.x;
    for (int i = tid; i < 128; i += 256) {
        g_bias[OB1 + i] = (i < 100) ? rdany(p.ob1, i, isf32) : 0.f;
        g_bias[UB1 + i] = (i < 100) ? rdany(p.ub1, i, isf32) : 0.f;
        g_bias[RB1 + i] = (i < 100) ? rdany(p.rb1, i, isf32) : 0.f;
        g_bias[NB1 + i] = (i < 100) ? rdany(p.nb1, i, isf32) : 0.f;
        g_bias[TB1 + i] = (i < 100) ? rdany(p.tb1, i, isf32) : 0.f;
        g_bias[NB2 + i] = rdany(p.nb2, i, isf32);
        g_bias[TB2 + i] = rdany(p.tb2, i, isf32);
        g_bias[DTS + i] = (i == 0) ? -0.01f
                                   : (rdany(p.tps, 127 - i, isf32) - rdany(p.tps, 128 - i, isf32));
    }
    for (int i = tid; i < 64; i += 256) {
        g_bias[OB2 + i] = rdany(p.ob2, i, isf32);
        g_bias[UB2 + i] = rdany(p.ub2, i, isf32);
        g_bias[RB2 + i] = rdany(p.rb2, i, isf32);
    }
}

struct MainP {
    const void *data, *tps;
    void* out;
};

#define WLOAD(off, KSn, nt, ks) (*(const s8*)(pk + (off) + (((((nt) * (KSn)) + (ks)) << 6) + lane) * 8))
#define MFMA(a, b, c) __builtin_amdgcn_mfma_f32_16x16x32_bf16((a), (b), (c), 0, 0, 0)

__global__ __launch_bounds__(512, 4) void enc_main(MainP p) {
    __shared__ u16 s_x[2][2048];   // [16][128] bf16 swizzled, double buffered
    __shared__ u16 s_yc[2048];     // [y_mu | s] bf16 swizzled
    __shared__ u16 s_yc2[2048];    // [y_mu*r | s*r]
    __shared__ u16 s_hA[2048];     // h buffer (hode/hu/hns)
    __shared__ u16 s_hB[2048];     // hr
    __shared__ float s_yo[16 * 65];  // y_ode, stride 65 (conflict-free)
    __shared__ float s_u[16 * 65];   // update gate, stride 65
    __shared__ float s_b[NBIAS];

    int tid = threadIdx.x, lane = tid & 63, w = tid >> 6;   // w = 0..7
    int btraj = blockIdx.x * MROWS;
    const u16* pk = g_pack;
    int isf32 = is_f32(p.tps);

    for (int i = tid; i < NBIAS; i += 512) s_b[i] = g_bias[i];
    for (int i = tid; i < 2048; i += 512) s_yc[i] = 0;

    // persistent per-wave layer-1 weight fragments (nt = w)
    s8 wl1u[8], wl1r[8], wl1n[8];   // K=256 nets: 8 k-slices each
    s8 wod1[2];                     // ODE layer1: K=64
#pragma unroll
    for (int ks = 0; ks < 8; ++ks) {
        wl1u[ks] = WLOAD(OFF_UG1, 8, w, ks);
        wl1r[ks] = WLOAD(OFF_RG1, 8, w, ks);
        wl1n[ks] = WLOAD(OFF_NS1, 8, w, ks);
    }
    wod1[0] = WLOAD(OFF_OD1, 2, w, 0);
    wod1[1] = WLOAD(OFF_OD1, 2, w, 1);

    // register-resident recurrent state:
    //  waves 0-3: ymu_r (y_mu), yo_r (y_ode), u_r (update gate) at col=colw
    //  waves 4-7: s_r (y_std) at col=colw-64
    f4 ymu_r = {0.f, 0.f, 0.f, 0.f};
    f4 s_r = {0.f, 0.f, 0.f, 0.f};
    f4 yo_r = {0.f, 0.f, 0.f, 0.f};
    f4 u_r = {0.f, 0.f, 0.f, 0.f};

    // x prefetch: each of 512 threads owns 4 elems; rows 8-15 duplicate rows 0-7
    int xrow = tid >> 5, xk = tid & 31;
    int xsrc = xrow & (MROWS - 1);           // clamp to valid trajectories
    int xoff = (xrow << 8) + ((xk << 3) ^ ((xrow & 7) << 4));
    {
        s4 xr = load_x4(p.data, ((size_t)(btraj + xsrc) * TSTEPS + 127) * INPD + (xk << 2), isf32);
        *(s4*)((char*)s_x[0] + xoff) = xr;
    }
    __syncthreads();

    const f4 zero4 = {0.f, 0.f, 0.f, 0.f};
    int colw = (w << 4) + (lane & 15);       // this wave's output column (0..127)
    int rbase = (lane >> 4) << 2;            // first of 4 output rows

    for (int it = 0; it < TSTEPS; ++it) {
        int cur = it & 1;
        float dt = s_b[DTS + it];

        // prefetch next x (issue early; store in phase F)
        s4 xnext;
        if (it < 127) {
            xnext = load_x4(p.data, ((size_t)(btraj + xsrc) * TSTEPS + (126 - it)) * INPD + (xk << 2), isf32);
        }

        // accumulators for u1/r1, built up across phases A and C
        f4 au = zero4, ar = zero4;

        // ---- Phase A: ODE layer 1 + u1/r1 partials over s (ks2,3) and x (ks4-7) ----
        {
            f4 ao = zero4;
            ao = MFMA(aread(s_yc, lane, 0), wod1[0], ao);
            ao = MFMA(aread(s_yc, lane, 1), wod1[1], ao);
#pragma unroll
            for (int ks = 2; ks < 4; ++ks) {
                s8 a = aread(s_yc, lane, ks);
                au = MFMA(a, wl1u[ks], au);
                ar = MFMA(a, wl1r[ks], ar);
            }
#pragma unroll
            for (int ks = 0; ks < 4; ++ks) {
                s8 a = aread(s_x[cur], lane, ks);
                au = MFMA(a, wl1u[4 + ks], au);
                ar = MFMA(a, wl1r[4 + ks], ar);
            }
            float bias = s_b[OB1 + colw];
#pragma unroll
            for (int j = 0; j < 4; ++j)
                hwrite(s_hA, rbase + j, colw, tanh_(ao[j] + bias));
        }
        __syncthreads();

        // ---- Phase B: ODE layer 2 -> y_ode (waves 0-3) ----
        if (w < 4) {
            s8 wod2[4];
#pragma unroll
            for (int ks = 0; ks < 4; ++ks) wod2[ks] = WLOAD(OFF_OD2, 4, w, ks);
            f4 ac = zero4;
#pragma unroll
            for (int ks = 0; ks < 4; ++ks) ac = MFMA(aread(s_hA, lane, ks), wod2[ks], ac);
            float bias = s_b[OB2 + colw];
#pragma unroll
            for (int j = 0; j < 4; ++j) {
                int rowt = rbase + j;
                float yo = ymu_r[j] + (ac[j] + bias) * dt;
                yo_r[j] = yo;
                s_yo[rowt * 65 + colw] = yo;
                hwrite(s_yc, rowt, colw, yo);
            }
        }
        __syncthreads();

        // ---- Phase C: u1/r1 finish with y_ode part (ks0,1) ----
        {
#pragma unroll
            for (int ks = 0; ks < 2; ++ks) {
                s8 a = aread(s_yc, lane, ks);
                au = MFMA(a, wl1u[ks], au);
                ar = MFMA(a, wl1r[ks], ar);
            }
            float bu = s_b[UB1 + colw], br = s_b[RB1 + colw];
#pragma unroll
            for (int j = 0; j < 4; ++j) {
                int rowt = rbase + j;
                hwrite(s_hA, rowt, colw, tanh_(au[j] + bu));
                hwrite(s_hB, rowt, colw, tanh_(ar[j] + br));
            }
        }
        __syncthreads();

        // ---- Phase D: u2 (waves 0-3) / r2 + build yc2 (waves 4-7) ----
        if (w < 4) {
            s8 w2[4];
#pragma unroll
            for (int ks = 0; ks < 4; ++ks) w2[ks] = WLOAD(OFF_UG2, 4, w, ks);
            f4 uac = zero4;
#pragma unroll
            for (int ks = 0; ks < 4; ++ks) uac = MFMA(aread(s_hA, lane, ks), w2[ks], uac);
            float bu = s_b[UB2 + colw];
#pragma unroll
            for (int j = 0; j < 4; ++j) {
                float uv = sigm(uac[j] + bu);
                u_r[j] = uv;
                s_u[(rbase + j) * 65 + colw] = uv;
            }
        } else {
            s8 w2[4];
#pragma unroll
            for (int ks = 0; ks < 4; ++ks) w2[ks] = WLOAD(OFF_RG2, 4, w - 4, ks);
            f4 rac = zero4;
#pragma unroll
            for (int ks = 0; ks < 4; ++ks) rac = MFMA(aread(s_hB, lane, ks), w2[ks], rac);
            int col = colw - 64;
            float br = s_b[RB2 + col];
#pragma unroll
            for (int j = 0; j < 4; ++j) {
                int rowt = rbase + j;
                float rval = sigm(rac[j] + br);
                float yo = s_yo[rowt * 65 + col];
                hwrite(s_yc2, rowt, col, yo * rval);
                hwrite(s_yc2, rowt, 64 + col, s_r[j] * rval);
            }
        }
        __syncthreads();

        // ---- Phase E: ns layer 1 (A = [yc2 | x], K=256), all waves ----
        {
            f4 an = zero4;
#pragma unroll
            for (int ks = 0; ks < 4; ++ks) an = MFMA(aread(s_yc2, lane, ks), wl1n[ks], an);
#pragma unroll
            for (int ks = 0; ks < 4; ++ks) an = MFMA(aread(s_x[cur], lane, ks), wl1n[4 + ks], an);
            float bn = s_b[NB1 + colw];
#pragma unroll
            for (int j = 0; j < 4; ++j)
                hwrite(s_hA, rbase + j, colw, tanh_(an[j] + bn));
        }
        __syncthreads();

        // ---- Phase F: ns layer 2 + state update, all waves ----
        {
            s8 wn2[4];
#pragma unroll
            for (int ks = 0; ks < 4; ++ks) wn2[ks] = WLOAD(OFF_NS2, 4, w, ks);
            f4 fn = zero4;
#pragma unroll
            for (int ks = 0; ks < 4; ++ks) fn = MFMA(aread(s_hA, lane, ks), wn2[ks], fn);
            // store prefetched x into the other buffer
            if (it < 127) *(s4*)((char*)s_x[cur ^ 1] + xoff) = xnext;

            float bn = s_b[NB2 + colw];
            int c = colw & 63;
#pragma unroll
            for (int j = 0; j < 4; ++j) {
                int rowt = rbase + j;
                float nsv = fn[j] + bn;
                float m = b2f(sread(s_x[cur], rowt, 64 + c));
                if (w < 4) {
                    float mg = m * (1.f - u_r[j]);
                    float ny = yo_r[j] + mg * (nsv - yo_r[j]);
                    ymu_r[j] = ny;
                    hwrite(s_yc, rowt, c, ny);
                } else {
                    float uval = s_u[rowt * 65 + c];
                    float mg = m * (1.f - uval);
                    float nstd = fabsf(nsv);
                    float nss = s_r[j] + mg * (nstd - s_r[j]);
                    nss = fabsf(nss);
                    s_r[j] = nss;
                    hwrite(s_yc, rowt, 64 + c, nss);
                }
            }
        }
        __syncthreads();
    }

    // ---- Final: z = mlp2([y|s], tz) ----
    s8 wt1[4], wt2[4];
#pragma unroll
    for (int ks = 0; ks < 4; ++ks) {
        wt1[ks] = WLOAD(OFF_TZ1, 4, w, ks);
        wt2[ks] = WLOAD(OFF_TZ2, 4, w, ks);
    }
    {
        f4 t1 = zero4;
#pragma unroll
        for (int ks = 0; ks < 4; ++ks) t1 = MFMA(aread(s_yc, lane, ks), wt1[ks], t1);
        float bt = s_b[TB1 + colw];
#pragma unroll
        for (int j = 0; j < 4; ++j)
            hwrite(s_hA, rbase + j, colw, tanh_(t1[j] + bt));
    }
    __syncthreads();
    {
        f4 t2 = zero4;
#pragma unroll
        for (int ks = 0; ks < 4; ++ks) t2 = MFMA(aread(s_hA, lane, ks), wt2[ks], t2);
        float bt = s_b[TB2 + colw];
#pragma unroll
        for (int j = 0; j < 4; ++j) {
            int rowt = rbase + j;
            if (rowt >= MROWS) continue;     // rows 8-15 are clones
            int gtraj = btraj + rowt;
            float z = t2[j] + bt;
            size_t idx;
            float val;
            if (colw < 64) { idx = (size_t)gtraj * 64 + colw; val = z; }
            else { idx = (size_t)N_TRAJ * 64 + (size_t)gtraj * 64 + (colw - 64); val = fabsf(z); }
            if (isf32) ((float*)p.out)[idx] = val;
            else ((u16*)p.out)[idx] = f2b(val);
        }
    }
}

extern "C" void kernel_launch(void* const* d_in, const int* in_sizes, int n_in,
                              void* d_out, int out_size, void* d_ws, size_t ws_size,
                              hipStream_t stream) {
    PackP pp;
    // order: ug_w1, rg_w1, ns_w1, ode_w1, ug_w2, rg_w2, ns_w2, ode_w2, tz_w1, tz_w2
    const int srcIdx[10] = {2, 6, 10, 14, 4, 8, 12, 16, 18, 20};
    const int Kr[10] = {256, 256, 256, 64, 100, 100, 100, 100, 128, 100};
    const int Nr[10] = {100, 100, 100, 100, 64, 64, 128, 64, 100, 128};
    const int KS[10] = {8, 8, 8, 2, 4, 4, 4, 4, 4, 4};
    const int NT[10] = {8, 8, 8, 8, 4, 4, 8, 4, 8, 8};
    for (int i = 0; i < 10; ++i) {
        pp.src[i] = d_in[srcIdx[i]];
        pp.Kr[i] = Kr[i];
        pp.Nr[i] = Nr[i];
        pp.KS[i] = KS[i];
        pp.sz[i] = KS[i] * NT[i] * 512;
    }
    pp.tps = d_in[1];
    repack_kernel<<<(PACK_ELEMS + 255) / 256, 256, 0, stream>>>(pp);

    PrepP bp;
    bp.tps = d_in[1];
    bp.ob1 = d_in[15]; bp.ob2 = d_in[17];
    bp.ub1 = d_in[3];  bp.ub2 = d_in[5];
    bp.rb1 = d_in[7];  bp.rb2 = d_in[9];
    bp.nb1 = d_in[11]; bp.nb2 = d_in[13];
    bp.tb1 = d_in[19]; bp.tb2 = d_in[21];
    prep_bias<<<1, 256, 0, stream>>>(bp);

    MainP mp;
    mp.data = d_in[0];
    mp.tps = d_in[1];
    mp.out = d_out;
    enc_main<<<N_TRAJ / MROWS, 512, 0, stream>>>(mp);
}

// Round 7
// 427.949 us; speedup vs baseline: 6.0902x; 6.0902x over previous
//
#include <hip/hip_runtime.h>

typedef unsigned short u16;
typedef __attribute__((ext_vector_type(8))) short s8;
typedef __attribute__((ext_vector_type(4))) short s4;
typedef __attribute__((ext_vector_type(4))) float f4;

#define N_TRAJ 4096
#define TSTEPS 128
#define LATD   64
#define INPD   128

// bias offsets (floats)
#define OB1 0
#define OB2 128
#define UB1 192
#define UB2 320
#define RB1 384
#define RB2 512
#define NB1 576
#define NB2 704
#define TB1 832
#define TB2 960
#define DTS 1088
#define NBIAS 1216

// packed weight offsets (elements)
#define OFF_UG1 0
#define OFF_RG1 32768
#define OFF_NS1 65536
#define OFF_OD1 98304
#define OFF_UG2 106496
#define OFF_RG2 114688
#define OFF_NS2 122880
#define OFF_OD2 139264
#define OFF_TZ1 147456
#define OFF_TZ2 163840
#define PACK_ELEMS 180224

// LDS-staged layer-2 weight segment offsets (elements, relative to s_w2)
// g_pack layout UG2|RG2|NS2|OD2 is contiguous from OFF_UG2 (40960 elems total)
#define LUG2 0
#define LRG2 8192
#define LNS2 16384
#define LOD2 32768
#define LW2_ELEMS 40960

__device__ u16 g_pack[PACK_ELEMS];
__device__ float g_bias[NBIAS];

__device__ __forceinline__ float b2f(u16 u) {
    union { unsigned int i; float f; } v; v.i = ((unsigned int)u) << 16; return v.f;
}
__device__ __forceinline__ u16 f2b(float f) {
    unsigned int x = __float_as_uint(f);
    unsigned int r = (x + 0x7FFFu + ((x >> 16) & 1u)) >> 16;
    return (u16)r;
}
__device__ __forceinline__ int is_f32(const void* tps) {
    return (*(const unsigned int*)tps) == 0u;  // f32: bits(0.0f)==0; bf16: u16 pair (0, 0x3C81) != 0
}
__device__ __forceinline__ float rdany(const void* a, int i, int isf32) {
    return isf32 ? ((const float*)a)[i] : b2f(((const u16*)a)[i]);
}
__device__ __forceinline__ float sigm(float x) {
    x = fminf(fmaxf(x, -30.f), 30.f);
    float e = __expf(-x);
    return __builtin_amdgcn_rcpf(1.f + e);
}
__device__ __forceinline__ float tanh_(float x) {
    x = fminf(fmaxf(x, -15.f), 15.f);
    float e = __expf(-2.f * x);
    return (1.f - e) * __builtin_amdgcn_rcpf(1.f + e);
}

// A-fragment read from a [16][128] bf16 LDS tile (row stride 256B, XOR swizzled)
__device__ __forceinline__ s8 aread(const u16* buf, int lane, int ks) {
    int row = lane & 15;
    int b = (ks << 6) + ((lane >> 4) << 4);
    int off = (row << 8) + (b ^ ((row & 7) << 4));
    return *(const s8*)((const char*)buf + off);
}
__device__ __forceinline__ void hwrite(u16* buf, int rowt, int col, float v) {
    int off = (rowt << 8) + (((col << 1)) ^ ((rowt & 7) << 4));
    *(u16*)((char*)buf + off) = f2b(v);
}
__device__ __forceinline__ u16 sread(const u16* buf, int rowt, int col) {
    int off = (rowt << 8) + (((col << 1)) ^ ((rowt & 7) << 4));
    return *(const u16*)((const char*)buf + off);
}
// load 4 consecutive x elements as bf16, from either dtype
__device__ __forceinline__ s4 load_x4(const void* data, size_t elemIdx, int isf32) {
    s4 r;
    if (isf32) {
        f4 v = *(const f4*)((const float*)data + elemIdx);
#pragma unroll
        for (int j = 0; j < 4; ++j) r[j] = (short)f2b(v[j]);
    } else {
        r = *(const s4*)((const u16*)data + elemIdx);
    }
    return r;
}

struct PackP {
    const void* src[10];
    const void* tps;
    int Kr[10], Nr[10], KS[10], sz[10];
};

__global__ __launch_bounds__(256) void repack_kernel(PackP p) {
    int gid = blockIdx.x * 256 + threadIdx.x;
    if (gid >= PACK_ELEMS) return;
    int isf32 = is_f32(p.tps);
    int idx = gid, m = 0, base = 0;
    while (m < 10 && idx >= p.sz[m]) { idx -= p.sz[m]; base += p.sz[m]; ++m; }
    if (m >= 10) return;
    int i = idx & 7;
    int l = (idx >> 3) & 63;
    int rest = idx >> 9;
    int ks = rest % p.KS[m];
    int nt = rest / p.KS[m];
    int k = ks * 32 + ((l >> 4) << 3) + i;
    int n = nt * 16 + (l & 15);
    u16 v = 0;
    if (k < p.Kr[m] && n < p.Nr[m]) v = f2b(rdany(p.src[m], k * p.Nr[m] + n, isf32));
    g_pack[base + idx] = v;
}

struct PrepP {
    const void *tps, *ob1, *ob2, *ub1, *ub2, *rb1, *rb2, *nb1, *nb2, *tb1, *tb2;
};

__global__ __launch_bounds__(256) void prep_bias(PrepP p) {
    int isf32 = is_f32(p.tps);
    int tid = threadIdx.x;
    for (int i = tid; i < 128; i += 256) {
        g_bias[OB1 + i] = (i < 100) ? rdany(p.ob1, i, isf32) : 0.f;
        g_bias[UB1 + i] = (i < 100) ? rdany(p.ub1, i, isf32) : 0.f;
        g_bias[RB1 + i] = (i < 100) ? rdany(p.rb1, i, isf32) : 0.f;
        g_bias[NB1 + i] = (i < 100) ? rdany(p.nb1, i, isf32) : 0.f;
        g_bias[TB1 + i] = (i < 100) ? rdany(p.tb1, i, isf32) : 0.f;
        g_bias[NB2 + i] = rdany(p.nb2, i, isf32);
        g_bias[TB2 + i] = rdany(p.tb2, i, isf32);
        g_bias[DTS + i] = (i == 0) ? -0.01f
                                   : (rdany(p.tps, 127 - i, isf32) - rdany(p.tps, 128 - i, isf32));
    }
    for (int i = tid; i < 64; i += 256) {
        g_bias[OB2 + i] = rdany(p.ob2, i, isf32);
        g_bias[UB2 + i] = rdany(p.ub2, i, isf32);
        g_bias[RB2 + i] = rdany(p.rb2, i, isf32);
    }
}

struct MainP {
    const void *data, *tps;
    void* out;
};

#define WLOAD(off, KSn, nt, ks) (*(const s8*)(pk + (off) + (((((nt) * (KSn)) + (ks)) << 6) + lane) * 8))
#define LW(seg, nt, ks) (*(const s8*)(s_w2 + (seg) + ((((nt) * 4 + (ks)) << 6) + lane) * 8))
#define MFMA(a, b, c) __builtin_amdgcn_mfma_f32_16x16x32_bf16((a), (b), (c), 0, 0, 0)

__global__ __launch_bounds__(512, 2) void enc_main(MainP p) {
    __shared__ u16 s_x[2][2048];   // [16][128] bf16 swizzled, double buffered
    __shared__ u16 s_yc[2048];     // [y_mu | s] bf16 swizzled
    __shared__ u16 s_yc2[2048];    // [y_mu*r | s*r]
    __shared__ u16 s_hA[2048];     // h buffer (hode/hu/hns)
    __shared__ u16 s_hB[2048];     // hr
    __shared__ u16 s_w2[LW2_ELEMS]; // LDS-staged layer-2 weights UG2|RG2|NS2|OD2
    __shared__ float s_yo[16 * 65];  // y_ode, stride 65 (conflict-free)
    __shared__ float s_u[16 * 65];   // update gate, stride 65
    __shared__ float s_b[NBIAS];

    int tid = threadIdx.x, lane = tid & 63, w = tid >> 6;   // w = 0..7
    int btraj = blockIdx.x << 4;
    const u16* pk = g_pack;
    int isf32 = is_f32(p.tps);

    for (int i = tid; i < NBIAS; i += 512) s_b[i] = g_bias[i];
    for (int i = tid; i < 2048; i += 512) s_yc[i] = 0;
    // stage layer-2 weights into LDS (contiguous range in g_pack)
    for (int i = tid; i < LW2_ELEMS / 8; i += 512)
        *(s8*)(s_w2 + i * 8) = *(const s8*)(pk + OFF_UG2 + i * 8);

    // persistent per-wave layer-1 weight fragments (nt = w)
    s8 wl1u[8], wl1r[8], wl1n[8];   // K=256 nets: 8 k-slices each
    s8 wod1[2];                     // ODE layer1: K=64
#pragma unroll
    for (int ks = 0; ks < 8; ++ks) {
        wl1u[ks] = WLOAD(OFF_UG1, 8, w, ks);
        wl1r[ks] = WLOAD(OFF_RG1, 8, w, ks);
        wl1n[ks] = WLOAD(OFF_NS1, 8, w, ks);
    }
    wod1[0] = WLOAD(OFF_OD1, 2, w, 0);
    wod1[1] = WLOAD(OFF_OD1, 2, w, 1);

    // register-resident recurrent state:
    //  waves 0-3: ymu_r (y_mu), yo_r (y_ode), u_r (update gate) at col=colw
    //  waves 4-7: s_r (y_std) at col=colw-64
    f4 ymu_r = {0.f, 0.f, 0.f, 0.f};
    f4 s_r = {0.f, 0.f, 0.f, 0.f};
    f4 yo_r = {0.f, 0.f, 0.f, 0.f};
    f4 u_r = {0.f, 0.f, 0.f, 0.f};

    // x prefetch: each of 512 threads owns 4 elems
    int xrow = tid >> 5, xk = tid & 31;
    int xoff = (xrow << 8) + ((xk << 3) ^ ((xrow & 7) << 4));
    {
        s4 xr = load_x4(p.data, ((size_t)(btraj + xrow) * TSTEPS + 127) * INPD + (xk << 2), isf32);
        *(s4*)((char*)s_x[0] + xoff) = xr;
    }
    __syncthreads();

    const f4 zero4 = {0.f, 0.f, 0.f, 0.f};
    int colw = (w << 4) + (lane & 15);       // this wave's output column (0..127)
    int rbase = (lane >> 4) << 2;            // first of 4 output rows

    for (int it = 0; it < TSTEPS; ++it) {
        int cur = it & 1;
        float dt = s_b[DTS + it];

        // prefetch next x (issue early; store in phase F)
        s4 xnext;
        if (it < 127) {
            xnext = load_x4(p.data, ((size_t)(btraj + xrow) * TSTEPS + (126 - it)) * INPD + (xk << 2), isf32);
        }

        // accumulators for u1/r1, built up across phases A and C
        f4 au = zero4, ar = zero4;

        // ---- Phase A: ODE layer 1 + u1/r1 partials over s (ks2,3) and x (ks4-7) ----
        {
            f4 ao = zero4;
            ao = MFMA(aread(s_yc, lane, 0), wod1[0], ao);
            ao = MFMA(aread(s_yc, lane, 1), wod1[1], ao);
#pragma unroll
            for (int ks = 2; ks < 4; ++ks) {
                s8 a = aread(s_yc, lane, ks);
                au = MFMA(a, wl1u[ks], au);
                ar = MFMA(a, wl1r[ks], ar);
            }
#pragma unroll
            for (int ks = 0; ks < 4; ++ks) {
                s8 a = aread(s_x[cur], lane, ks);
                au = MFMA(a, wl1u[4 + ks], au);
                ar = MFMA(a, wl1r[4 + ks], ar);
            }
            float bias = s_b[OB1 + colw];
#pragma unroll
            for (int j = 0; j < 4; ++j)
                hwrite(s_hA, rbase + j, colw, tanh_(ao[j] + bias));
        }
        __syncthreads();

        // ---- Phase B: ODE layer 2 -> y_ode (waves 0-3) ----
        if (w < 4) {
            s8 wod2[4];
#pragma unroll
            for (int ks = 0; ks < 4; ++ks) wod2[ks] = LW(LOD2, w, ks);
            f4 ac = zero4;
#pragma unroll
            for (int ks = 0; ks < 4; ++ks) ac = MFMA(aread(s_hA, lane, ks), wod2[ks], ac);
            float bias = s_b[OB2 + colw];
#pragma unroll
            for (int j = 0; j < 4; ++j) {
                int rowt = rbase + j;
                float yo = ymu_r[j] + (ac[j] + bias) * dt;
                yo_r[j] = yo;
                s_yo[rowt * 65 + colw] = yo;
                hwrite(s_yc, rowt, colw, yo);
            }
        }
        __syncthreads();

        // ---- Phase C: u1/r1 finish with y_ode part (ks0,1) ----
        {
#pragma unroll
            for (int ks = 0; ks < 2; ++ks) {
                s8 a = aread(s_yc, lane, ks);
                au = MFMA(a, wl1u[ks], au);
                ar = MFMA(a, wl1r[ks], ar);
            }
            float bu = s_b[UB1 + colw], br = s_b[RB1 + colw];
#pragma unroll
            for (int j = 0; j < 4; ++j) {
                int rowt = rbase + j;
                hwrite(s_hA, rowt, colw, tanh_(au[j] + bu));
                hwrite(s_hB, rowt, colw, tanh_(ar[j] + br));
            }
        }
        __syncthreads();

        // ---- Phase D: u2 (waves 0-3) / r2 + build yc2 (waves 4-7), + ns1 x-part (all) ----
        f4 an = zero4;
        {
#pragma unroll
            for (int ks = 0; ks < 4; ++ks)
                an = MFMA(aread(s_x[cur], lane, ks), wl1n[4 + ks], an);
        }
        if (w < 4) {
            s8 w2[4];
#pragma unroll
            for (int ks = 0; ks < 4; ++ks) w2[ks] = LW(LUG2, w, ks);
            f4 uac = zero4;
#pragma unroll
            for (int ks = 0; ks < 4; ++ks) uac = MFMA(aread(s_hA, lane, ks), w2[ks], uac);
            float bu = s_b[UB2 + colw];
#pragma unroll
            for (int j = 0; j < 4; ++j) {
                float uv = sigm(uac[j] + bu);
                u_r[j] = uv;
                s_u[(rbase + j) * 65 + colw] = uv;
            }
        } else {
            s8 w2[4];
#pragma unroll
            for (int ks = 0; ks < 4; ++ks) w2[ks] = LW(LRG2, w - 4, ks);
            f4 rac = zero4;
#pragma unroll
            for (int ks = 0; ks < 4; ++ks) rac = MFMA(aread(s_hB, lane, ks), w2[ks], rac);
            int col = colw - 64;
            float br = s_b[RB2 + col];
#pragma unroll
            for (int j = 0; j < 4; ++j) {
                int rowt = rbase + j;
                float rval = sigm(rac[j] + br);
                float yo = s_yo[rowt * 65 + col];
                hwrite(s_yc2, rowt, col, yo * rval);
                hwrite(s_yc2, rowt, 64 + col, s_r[j] * rval);
            }
        }
        __syncthreads();

        // ---- Phase E: ns layer 1 finish (A = yc2, K=128), all waves ----
        {
#pragma unroll
            for (int ks = 0; ks < 4; ++ks) an = MFMA(aread(s_yc2, lane, ks), wl1n[ks], an);
            float bn = s_b[NB1 + colw];
#pragma unroll
            for (int j = 0; j < 4; ++j)
                hwrite(s_hA, rbase + j, colw, tanh_(an[j] + bn));
        }
        __syncthreads();

        // ---- Phase F: ns layer 2 + state update, all waves ----
        {
            s8 wn2[4];
#pragma unroll
            for (int ks = 0; ks < 4; ++ks) wn2[ks] = LW(LNS2, w, ks);
            f4 fn = zero4;
#pragma unroll
            for (int ks = 0; ks < 4; ++ks) fn = MFMA(aread(s_hA, lane, ks), wn2[ks], fn);
            // store prefetched x into the other buffer
            if (it < 127) *(s4*)((char*)s_x[cur ^ 1] + xoff) = xnext;

            float bn = s_b[NB2 + colw];
            int c = colw & 63;
#pragma unroll
            for (int j = 0; j < 4; ++j) {
                int rowt = rbase + j;
                float nsv = fn[j] + bn;
                float m = b2f(sread(s_x[cur], rowt, 64 + c));
                if (w < 4) {
                    float mg = m * (1.f - u_r[j]);
                    float ny = yo_r[j] + mg * (nsv - yo_r[j]);
                    ymu_r[j] = ny;
                    hwrite(s_yc, rowt, c, ny);
                } else {
                    float uval = s_u[rowt * 65 + c];
                    float mg = m * (1.f - uval);
                    float nstd = fabsf(nsv);
                    float nss = s_r[j] + mg * (nstd - s_r[j]);
                    nss = fabsf(nss);
                    s_r[j] = nss;
                    hwrite(s_yc, rowt, 64 + c, nss);
                }
            }
        }
        __syncthreads();
    }

    // ---- Final: z = mlp2([y|s], tz) ----
    s8 wt1[4], wt2[4];
#pragma unroll
    for (int ks = 0; ks < 4; ++ks) {
        wt1[ks] = WLOAD(OFF_TZ1, 4, w, ks);
        wt2[ks] = WLOAD(OFF_TZ2, 4, w, ks);
    }
    {
        f4 t1 = zero4;
#pragma unroll
        for (int ks = 0; ks < 4; ++ks) t1 = MFMA(aread(s_yc, lane, ks), wt1[ks], t1);
        float bt = s_b[TB1 + colw];
#pragma unroll
        for (int j = 0; j < 4; ++j)
            hwrite(s_hA, rbase + j, colw, tanh_(t1[j] + bt));
    }
    __syncthreads();
    {
        f4 t2 = zero4;
#pragma unroll
        for (int ks = 0; ks < 4; ++ks) t2 = MFMA(aread(s_hA, lane, ks), wt2[ks], t2);
        float bt = s_b[TB2 + colw];
#pragma unroll
        for (int j = 0; j < 4; ++j) {
            int gtraj = btraj + rbase + j;
            float z = t2[j] + bt;
            size_t idx;
            float val;
            if (colw < 64) { idx = (size_t)gtraj * 64 + colw; val = z; }
            else { idx = (size_t)N_TRAJ * 64 + (size_t)gtraj * 64 + (colw - 64); val = fabsf(z); }
            if (isf32) ((float*)p.out)[idx] = val;
            else ((u16*)p.out)[idx] = f2b(val);
        }
    }
}

extern "C" void kernel_launch(void* const* d_in, const int* in_sizes, int n_in,
                              void* d_out, int out_size, void* d_ws, size_t ws_size,
                              hipStream_t stream) {
    PackP pp;
    // order: ug_w1, rg_w1, ns_w1, ode_w1, ug_w2, rg_w2, ns_w2, ode_w2, tz_w1, tz_w2
    const int srcIdx[10] = {2, 6, 10, 14, 4, 8, 12, 16, 18, 20};
    const int Kr[10] = {256, 256, 256, 64, 100, 100, 100, 100, 128, 100};
    const int Nr[10] = {100, 100, 100, 100, 64, 64, 128, 64, 100, 128};
    const int KS[10] = {8, 8, 8, 2, 4, 4, 4, 4, 4, 4};
    const int NT[10] = {8, 8, 8, 8, 4, 4, 8, 4, 8, 8};
    for (int i = 0; i < 10; ++i) {
        pp.src[i] = d_in[srcIdx[i]];
        pp.Kr[i] = Kr[i];
        pp.Nr[i] = Nr[i];
        pp.KS[i] = KS[i];
        pp.sz[i] = KS[i] * NT[i] * 512;
    }
    pp.tps = d_in[1];
    repack_kernel<<<(PACK_ELEMS + 255) / 256, 256, 0, stream>>>(pp);

    PrepP bp;
    bp.tps = d_in[1];
    bp.ob1 = d_in[15]; bp.ob2 = d_in[17];
    bp.ub1 = d_in[3];  bp.ub2 = d_in[5];
    bp.rb1 = d_in[7];  bp.rb2 = d_in[9];
    bp.nb1 = d_in[11]; bp.nb2 = d_in[13];
    bp.tb1 = d_in[19]; bp.tb2 = d_in[21];
    prep_bias<<<1, 256, 0, stream>>>(bp);

    MainP mp;
    mp.data = d_in[0];
    mp.tps = d_in[1];
    mp.out = d_out;
    enc_main<<<N_TRAJ / 16, 512, 0, stream>>>(mp);
}

// Round 8
// 380.351 us; speedup vs baseline: 6.8524x; 1.1251x over previous
//
#include <hip/hip_runtime.h>

typedef unsigned short u16;
typedef __attribute__((ext_vector_type(8))) short s8;
typedef __attribute__((ext_vector_type(4))) short s4;
typedef __attribute__((ext_vector_type(4))) float f4;

#define N_TRAJ 4096
#define TSTEPS 128
#define LATD   64
#define INPD   128

// bias offsets (floats)
#define OB1 0
#define OB2 128
#define UB1 192
#define UB2 320
#define RB1 384
#define RB2 512
#define NB1 576
#define NB2 704
#define TB1 832
#define TB2 960
#define DTS 1088
#define NBIAS 1216

// packed weight offsets (elements)
#define OFF_UG1 0
#define OFF_RG1 32768
#define OFF_NS1 65536
#define OFF_OD1 98304
#define OFF_UG2 106496
#define OFF_RG2 114688
#define OFF_NS2 122880
#define OFF_OD2 139264
#define OFF_TZ1 147456
#define OFF_TZ2 163840
#define PACK_ELEMS 180224

// LDS-staged layer-2 weight segment offsets (elements, relative to s_w2)
#define LUG2 0
#define LRG2 8192
#define LNS2 16384
#define LOD2 32768
#define LW2_ELEMS 40960

#define SYO 68   // f32 state stride (4-aligned, bank-spread)

__device__ u16 g_pack[PACK_ELEMS];
__device__ float g_bias[NBIAS];

__device__ __forceinline__ float b2f(u16 u) {
    union { unsigned int i; float f; } v; v.i = ((unsigned int)u) << 16; return v.f;
}
__device__ __forceinline__ u16 f2b(float f) {
    unsigned int x = __float_as_uint(f);
    unsigned int r = (x + 0x7FFFu + ((x >> 16) & 1u)) >> 16;
    return (u16)r;
}
__device__ __forceinline__ unsigned int cvtpk(float lo, float hi) {
    unsigned int r;
    asm("v_cvt_pk_bf16_f32 %0, %1, %2" : "=v"(r) : "v"(lo), "v"(hi));
    return r;
}
__device__ __forceinline__ int is_f32(const void* tps) {
    return (*(const unsigned int*)tps) == 0u;
}
__device__ __forceinline__ float rdany(const void* a, int i, int isf32) {
    return isf32 ? ((const float*)a)[i] : b2f(((const u16*)a)[i]);
}
__device__ __forceinline__ float sigm(float x) {
    x = fminf(fmaxf(x, -30.f), 30.f);
    float e = __expf(-x);
    return __builtin_amdgcn_rcpf(1.f + e);
}
__device__ __forceinline__ float tanh_(float x) {
    x = fminf(fmaxf(x, -15.f), 15.f);
    float e = __expf(-2.f * x);
    return (1.f - e) * __builtin_amdgcn_rcpf(1.f + e);
}

// activation fragment read from a [16][128] bf16 LDS tile (row stride 256B, XOR swizzled)
// serves as the MFMA *B* operand now: lane l -> col (traj) = l&15, k = ks*32 + (l>>4)*8 + i
__device__ __forceinline__ s8 aread(const u16* buf, int lane, int ks) {
    int row = lane & 15;
    int b = (ks << 6) + ((lane >> 4) << 4);
    int off = (row << 8) + (b ^ ((row & 7) << 4));
    return *(const s8*)((const char*)buf + off);
}
// packed write of 4 consecutive bf16 cols for one traj row (swizzled, 8B aligned)
__device__ __forceinline__ void hwrite4(u16* buf, int traj, int ncol0, float a, float b, float c, float d) {
    int off = (traj << 8) + ((ncol0 << 1) ^ ((traj & 7) << 4));
    uint2 v;
    v.x = cvtpk(a, b);
    v.y = cvtpk(c, d);
    *(uint2*)((char*)buf + off) = v;
}
// packed read of 4 consecutive bf16 cols for one traj row
__device__ __forceinline__ s4 sread4(const u16* buf, int traj, int col0) {
    int off = (traj << 8) + ((col0 << 1) ^ ((traj & 7) << 4));
    return *(const s4*)((const char*)buf + off);
}
// load 4 consecutive x elements as bf16, from either dtype
__device__ __forceinline__ s4 load_x4(const void* data, size_t elemIdx, int isf32) {
    s4 r;
    if (isf32) {
        f4 v = *(const f4*)((const float*)data + elemIdx);
#pragma unroll
        for (int j = 0; j < 4; ++j) r[j] = (short)f2b(v[j]);
    } else {
        r = *(const s4*)((const u16*)data + elemIdx);
    }
    return r;
}

struct PackP {
    const void* src[10];
    const void* tps;
    int Kr[10], Nr[10], KS[10], sz[10];
};

__global__ __launch_bounds__(256) void repack_kernel(PackP p) {
    int gid = blockIdx.x * 256 + threadIdx.x;
    if (gid >= PACK_ELEMS) return;
    int isf32 = is_f32(p.tps);
    int idx = gid, m = 0, base = 0;
    while (m < 10 && idx >= p.sz[m]) { idx -= p.sz[m]; base += p.sz[m]; ++m; }
    if (m >= 10) return;
    int i = idx & 7;
    int l = (idx >> 3) & 63;
    int rest = idx >> 9;
    int ks = rest % p.KS[m];
    int nt = rest / p.KS[m];
    int k = ks * 32 + ((l >> 4) << 3) + i;
    int n = nt * 16 + (l & 15);
    u16 v = 0;
    if (k < p.Kr[m] && n < p.Nr[m]) v = f2b(rdany(p.src[m], k * p.Nr[m] + n, isf32));
    g_pack[base + idx] = v;
}

struct PrepP {
    const void *tps, *ob1, *ob2, *ub1, *ub2, *rb1, *rb2, *nb1, *nb2, *tb1, *tb2;
};

__global__ __launch_bounds__(256) void prep_bias(PrepP p) {
    int isf32 = is_f32(p.tps);
    int tid = threadIdx.x;
    for (int i = tid; i < 128; i += 256) {
        g_bias[OB1 + i] = (i < 100) ? rdany(p.ob1, i, isf32) : 0.f;
        g_bias[UB1 + i] = (i < 100) ? rdany(p.ub1, i, isf32) : 0.f;
        g_bias[RB1 + i] = (i < 100) ? rdany(p.rb1, i, isf32) : 0.f;
        g_bias[NB1 + i] = (i < 100) ? rdany(p.nb1, i, isf32) : 0.f;
        g_bias[TB1 + i] = (i < 100) ? rdany(p.tb1, i, isf32) : 0.f;
        g_bias[NB2 + i] = rdany(p.nb2, i, isf32);
        g_bias[TB2 + i] = rdany(p.tb2, i, isf32);
        g_bias[DTS + i] = (i == 0) ? -0.01f
                                   : (rdany(p.tps, 127 - i, isf32) - rdany(p.tps, 128 - i, isf32));
    }
    for (int i = tid; i < 64; i += 256) {
        g_bias[OB2 + i] = rdany(p.ob2, i, isf32);
        g_bias[UB2 + i] = rdany(p.ub2, i, isf32);
        g_bias[RB2 + i] = rdany(p.rb2, i, isf32);
    }
}

struct MainP {
    const void *data, *tps;
    void* out;
};

#define WLOAD(off, KSn, nt, ks) (*(const s8*)(pk + (off) + (((((nt) * (KSn)) + (ks)) << 6) + lane) * 8))
#define LW(seg, nt, ks) (*(const s8*)(s_w2 + (seg) + ((((nt) * 4 + (ks)) << 6) + lane) * 8))
// TRANSPOSED: A = weight fragment, B = activation fragment -> C[ncol][traj]
#define MFMA(wf, af, c) __builtin_amdgcn_mfma_f32_16x16x32_bf16((wf), (af), (c), 0, 0, 0)

__global__ __launch_bounds__(512, 2) void enc_main(MainP p) {
    __shared__ u16 s_x[2][2048];   // [16][128] bf16 swizzled, double buffered
    __shared__ u16 s_yc[2048];     // [y_mu | s] bf16 swizzled
    __shared__ u16 s_yc2[2048];    // [y_mu*r | s*r]
    __shared__ u16 s_hA[2048];     // h buffer (hode/hu/hns)
    __shared__ u16 s_hB[2048];     // hr
    __shared__ u16 s_w2[LW2_ELEMS]; // LDS-staged layer-2 weights UG2|RG2|NS2|OD2
    __shared__ float s_yo[16 * SYO]; // y_ode
    __shared__ float s_u[16 * SYO];  // update gate
    __shared__ float s_b[NBIAS];

    int tid = threadIdx.x, lane = tid & 63, w = tid >> 6;   // w = 0..7
    int btraj = blockIdx.x << 4;
    const u16* pk = g_pack;
    int isf32 = is_f32(p.tps);

    for (int i = tid; i < NBIAS; i += 512) s_b[i] = g_bias[i];
    for (int i = tid; i < 2048; i += 512) s_yc[i] = 0;
    for (int i = tid; i < LW2_ELEMS / 8; i += 512)
        *(s8*)(s_w2 + i * 8) = *(const s8*)(pk + OFF_UG2 + i * 8);

    // persistent per-wave layer-1 weight fragments (nt = w)
    s8 wl1u[8], wl1r[8], wl1n[8];
    s8 wod1[2];
#pragma unroll
    for (int ks = 0; ks < 8; ++ks) {
        wl1u[ks] = WLOAD(OFF_UG1, 8, w, ks);
        wl1r[ks] = WLOAD(OFF_RG1, 8, w, ks);
        wl1n[ks] = WLOAD(OFF_NS1, 8, w, ks);
    }
    wod1[0] = WLOAD(OFF_OD1, 2, w, 0);
    wod1[1] = WLOAD(OFF_OD1, 2, w, 1);

    // register-resident recurrent state, TRANSPOSED labeling:
    //  thread owns traj = lane&15, ncols nbase..nbase+3 where nbase = 16w + 4*(lane>>4)
    //  waves 0-3: ymu_r, yo_r, u_r (y-cols 0..63); waves 4-7: s_r (s-cols nbase-64..)
    f4 ymu_r = {0.f, 0.f, 0.f, 0.f};
    f4 s_r = {0.f, 0.f, 0.f, 0.f};
    f4 yo_r = {0.f, 0.f, 0.f, 0.f};
    f4 u_r = {0.f, 0.f, 0.f, 0.f};

    // x prefetch: each of 512 threads owns 4 elems
    int xrow = tid >> 5, xk = tid & 31;
    int xoff = (xrow << 8) + ((xk << 3) ^ ((xrow & 7) << 4));
    {
        s4 xr = load_x4(p.data, ((size_t)(btraj + xrow) * TSTEPS + 127) * INPD + (xk << 2), isf32);
        *(s4*)((char*)s_x[0] + xoff) = xr;
    }
    __syncthreads();

    const f4 zero4 = {0.f, 0.f, 0.f, 0.f};
    int traj = lane & 15;
    int nbase = (w << 4) + ((lane >> 4) << 2);   // first of 4 owned output cols (0..127)

    for (int it = 0; it < TSTEPS; ++it) {
        int cur = it & 1;
        float dt = s_b[DTS + it];

        s4 xnext;
        if (it < 127) {
            xnext = load_x4(p.data, ((size_t)(btraj + xrow) * TSTEPS + (126 - it)) * INPD + (xk << 2), isf32);
        }

        f4 au = zero4, ar = zero4;

        // ---- Phase A: ODE layer 1 + u1/r1 partials over s (ks2,3) and x (ks4-7) ----
        {
            f4 ao = zero4;
            ao = MFMA(wod1[0], aread(s_yc, lane, 0), ao);
            ao = MFMA(wod1[1], aread(s_yc, lane, 1), ao);
#pragma unroll
            for (int ks = 2; ks < 4; ++ks) {
                s8 a = aread(s_yc, lane, ks);
                au = MFMA(wl1u[ks], a, au);
                ar = MFMA(wl1r[ks], a, ar);
            }
#pragma unroll
            for (int ks = 0; ks < 4; ++ks) {
                s8 a = aread(s_x[cur], lane, ks);
                au = MFMA(wl1u[4 + ks], a, au);
                ar = MFMA(wl1r[4 + ks], a, ar);
            }
            f4 b4 = *(const f4*)(s_b + OB1 + nbase);
            hwrite4(s_hA, traj, nbase, tanh_(ao[0] + b4[0]), tanh_(ao[1] + b4[1]),
                    tanh_(ao[2] + b4[2]), tanh_(ao[3] + b4[3]));
        }
        __syncthreads();

        // ---- Phase B: ODE layer 2 -> y_ode (waves 0-3) ----
        if (w < 4) {
            s8 wod2[4];
#pragma unroll
            for (int ks = 0; ks < 4; ++ks) wod2[ks] = LW(LOD2, w, ks);
            f4 ac = zero4;
#pragma unroll
            for (int ks = 0; ks < 4; ++ks) ac = MFMA(wod2[ks], aread(s_hA, lane, ks), ac);
            f4 b4 = *(const f4*)(s_b + OB2 + nbase);
#pragma unroll
            for (int j = 0; j < 4; ++j) yo_r[j] = ymu_r[j] + (ac[j] + b4[j]) * dt;
            *(f4*)(s_yo + traj * SYO + nbase) = yo_r;
            hwrite4(s_yc, traj, nbase, yo_r[0], yo_r[1], yo_r[2], yo_r[3]);
        }
        __syncthreads();

        // ---- Phase C: u1/r1 finish with y_ode part (ks0,1) ----
        {
#pragma unroll
            for (int ks = 0; ks < 2; ++ks) {
                s8 a = aread(s_yc, lane, ks);
                au = MFMA(wl1u[ks], a, au);
                ar = MFMA(wl1r[ks], a, ar);
            }
            f4 bu4 = *(const f4*)(s_b + UB1 + nbase);
            f4 br4 = *(const f4*)(s_b + RB1 + nbase);
            hwrite4(s_hA, traj, nbase, tanh_(au[0] + bu4[0]), tanh_(au[1] + bu4[1]),
                    tanh_(au[2] + bu4[2]), tanh_(au[3] + bu4[3]));
            hwrite4(s_hB, traj, nbase, tanh_(ar[0] + br4[0]), tanh_(ar[1] + br4[1]),
                    tanh_(ar[2] + br4[2]), tanh_(ar[3] + br4[3]));
        }
        __syncthreads();

        // ---- Phase D: ns1 x-part (all) + u2 (waves 0-3) / r2 + build yc2 (waves 4-7) ----
        f4 an = zero4;
        {
#pragma unroll
            for (int ks = 0; ks < 4; ++ks)
                an = MFMA(wl1n[4 + ks], aread(s_x[cur], lane, ks), an);
        }
        if (w < 4) {
            s8 w2[4];
#pragma unroll
            for (int ks = 0; ks < 4; ++ks) w2[ks] = LW(LUG2, w, ks);
            f4 uac = zero4;
#pragma unroll
            for (int ks = 0; ks < 4; ++ks) uac = MFMA(w2[ks], aread(s_hA, lane, ks), uac);
            f4 b4 = *(const f4*)(s_b + UB2 + nbase);
#pragma unroll
            for (int j = 0; j < 4; ++j) u_r[j] = sigm(uac[j] + b4[j]);
            *(f4*)(s_u + traj * SYO + nbase) = u_r;
        } else {
            s8 w2[4];
#pragma unroll
            for (int ks = 0; ks < 4; ++ks) w2[ks] = LW(LRG2, w - 4, ks);
            f4 rac = zero4;
#pragma unroll
            for (int ks = 0; ks < 4; ++ks) rac = MFMA(w2[ks], aread(s_hB, lane, ks), rac);
            int sb = nbase - 64;
            f4 b4 = *(const f4*)(s_b + RB2 + sb);
            f4 yo4 = *(const f4*)(s_yo + traj * SYO + sb);
            f4 rv;
#pragma unroll
            for (int j = 0; j < 4; ++j) rv[j] = sigm(rac[j] + b4[j]);
            hwrite4(s_yc2, traj, sb, yo4[0] * rv[0], yo4[1] * rv[1], yo4[2] * rv[2], yo4[3] * rv[3]);
            hwrite4(s_yc2, traj, nbase, s_r[0] * rv[0], s_r[1] * rv[1], s_r[2] * rv[2], s_r[3] * rv[3]);
        }
        __syncthreads();

        // ---- Phase E: ns layer 1 finish (yc2 part), all waves ----
        {
#pragma unroll
            for (int ks = 0; ks < 4; ++ks) an = MFMA(wl1n[ks], aread(s_yc2, lane, ks), an);
            f4 b4 = *(const f4*)(s_b + NB1 + nbase);
            hwrite4(s_hA, traj, nbase, tanh_(an[0] + b4[0]), tanh_(an[1] + b4[1]),
                    tanh_(an[2] + b4[2]), tanh_(an[3] + b4[3]));
        }
        __syncthreads();

        // ---- Phase F: ns layer 2 + state update, all waves ----
        {
            s8 wn2[4];
#pragma unroll
            for (int ks = 0; ks < 4; ++ks) wn2[ks] = LW(LNS2, w, ks);
            f4 fn = zero4;
#pragma unroll
            for (int ks = 0; ks < 4; ++ks) fn = MFMA(wn2[ks], aread(s_hA, lane, ks), fn);
            if (it < 127) *(s4*)((char*)s_x[cur ^ 1] + xoff) = xnext;

            f4 b4 = *(const f4*)(s_b + NB2 + nbase);
            if (w < 4) {
                // mask cols 64 + ncol
                s4 mm = sread4(s_x[cur], traj, 64 + nbase);
#pragma unroll
                for (int j = 0; j < 4; ++j) {
                    float nsv = fn[j] + b4[j];
                    float m = b2f((u16)mm[j]);
                    float mg = m * (1.f - u_r[j]);
                    ymu_r[j] = yo_r[j] + mg * (nsv - yo_r[j]);
                }
                hwrite4(s_yc, traj, nbase, ymu_r[0], ymu_r[1], ymu_r[2], ymu_r[3]);
            } else {
                int sb = nbase - 64;
                // mask cols 64 + scol = nbase
                s4 mm = sread4(s_x[cur], traj, nbase);
                f4 u4 = *(const f4*)(s_u + traj * SYO + sb);
#pragma unroll
                for (int j = 0; j < 4; ++j) {
                    float nsv = fabsf(fn[j] + b4[j]);
                    float m = b2f((u16)mm[j]);
                    float mg = m * (1.f - u4[j]);
                    float nss = s_r[j] + mg * (nsv - s_r[j]);
                    s_r[j] = fabsf(nss);
                }
                hwrite4(s_yc, traj, nbase, s_r[0], s_r[1], s_r[2], s_r[3]);
            }
        }
        __syncthreads();
    }

    // ---- Final: z = mlp2([y|s], tz) ----
    s8 wt1[4], wt2[4];
#pragma unroll
    for (int ks = 0; ks < 4; ++ks) {
        wt1[ks] = WLOAD(OFF_TZ1, 4, w, ks);
        wt2[ks] = WLOAD(OFF_TZ2, 4, w, ks);
    }
    {
        f4 t1 = zero4;
#pragma unroll
        for (int ks = 0; ks < 4; ++ks) t1 = MFMA(wt1[ks], aread(s_yc, lane, ks), t1);
        f4 b4 = *(const f4*)(s_b + TB1 + nbase);
        hwrite4(s_hA, traj, nbase, tanh_(t1[0] + b4[0]), tanh_(t1[1] + b4[1]),
                tanh_(t1[2] + b4[2]), tanh_(t1[3] + b4[3]));
    }
    __syncthreads();
    {
        f4 t2 = zero4;
#pragma unroll
        for (int ks = 0; ks < 4; ++ks) t2 = MFMA(wt2[ks], aread(s_hA, lane, ks), t2);
        f4 b4 = *(const f4*)(s_b + TB2 + nbase);
        int gtraj = btraj + traj;
        f4 z;
        size_t base;
        if (w < 4) {
#pragma unroll
            for (int j = 0; j < 4; ++j) z[j] = t2[j] + b4[j];
            base = (size_t)gtraj * 64 + nbase;
        } else {
#pragma unroll
            for (int j = 0; j < 4; ++j) z[j] = fabsf(t2[j] + b4[j]);
            base = (size_t)N_TRAJ * 64 + (size_t)gtraj * 64 + (nbase - 64);
        }
        if (isf32) {
            *(f4*)((float*)p.out + base) = z;
        } else {
            uint2 pv;
            pv.x = cvtpk(z[0], z[1]);
            pv.y = cvtpk(z[2], z[3]);
            *(uint2*)((u16*)p.out + base) = pv;
        }
    }
}

extern "C" void kernel_launch(void* const* d_in, const int* in_sizes, int n_in,
                              void* d_out, int out_size, void* d_ws, size_t ws_size,
                              hipStream_t stream) {
    PackP pp;
    const int srcIdx[10] = {2, 6, 10, 14, 4, 8, 12, 16, 18, 20};
    const int Kr[10] = {256, 256, 256, 64, 100, 100, 100, 100, 128, 100};
    const int Nr[10] = {100, 100, 100, 100, 64, 64, 128, 64, 100, 128};
    const int KS[10] = {8, 8, 8, 2, 4, 4, 4, 4, 4, 4};
    const int NT[10] = {8, 8, 8, 8, 4, 4, 8, 4, 8, 8};
    for (int i = 0; i < 10; ++i) {
        pp.src[i] = d_in[srcIdx[i]];
        pp.Kr[i] = Kr[i];
        pp.Nr[i] = Nr[i];
        pp.KS[i] = KS[i];
        pp.sz[i] = KS[i] * NT[i] * 512;
    }
    pp.tps = d_in[1];
    repack_kernel<<<(PACK_ELEMS + 255) / 256, 256, 0, stream>>>(pp);

    PrepP bp;
    bp.tps = d_in[1];
    bp.ob1 = d_in[15]; bp.ob2 = d_in[17];
    bp.ub1 = d_in[3];  bp.ub2 = d_in[5];
    bp.rb1 = d_in[7];  bp.rb2 = d_in[9];
    bp.nb1 = d_in[11]; bp.nb2 = d_in[13];
    bp.tb1 = d_in[19]; bp.tb2 = d_in[21];
    prep_bias<<<1, 256, 0, stream>>>(bp);

    MainP mp;
    mp.data = d_in[0];
    mp.tps = d_in[1];
    mp.out = d_out;
    enc_main<<<N_TRAJ / 16, 512, 0, stream>>>(mp);
}